// Round 10
// baseline (405.026 us; speedup 1.0000x reference)
//
#include <hip/hip_runtime.h>
#include <math.h>

// Problem constants
#define NB 8
#define CC 512
#define NPIX 4096   // 64*64
#define HM 256

// Workspace layout (4-byte units). Total ~130.4 MiB.
#define WS_MS    0                  // [8][4096] m_s (f32)
#define WS_MBG   32768              // [8][4096] m_bg (f32)
#define WS_DIST  65536              // [8][4096] EDT (f32)
#define WS_CNT   98304              // [16]
#define WS_PC    98320              // [8][512] p_contrast (f32)
#define WS_GWP   102416             // [512][512] gate_w packed u32
#define WS_FWP   364560             // [512][512] fusion_w packed u32
#define WS_FSPK  626704             // [8][4096][512] f_s packed u32 ([p][c] layout!)
#define WS_FPPK  17403920           // [8][4096][512] f_pur packed u32

typedef __attribute__((ext_vector_type(8))) short short8;
typedef __attribute__((ext_vector_type(4))) float f32x4;

// ---- bf16 split helpers: u32 = (bf16(x)<<16) | bf16(x - bf16(x)) -----------
// 3-term Markidis split gives ~17-bit effective mantissa per product.
__device__ __forceinline__ uint32_t packbf(float x) {
    uint32_t b = __float_as_uint(x);
    uint32_t hi = (b + 0x7fffu + ((b >> 16) & 1u)) & 0xffff0000u;   // RNE to bf16
    float rem = x - __uint_as_float(hi);
    uint32_t rb = __float_as_uint(rem);
    uint32_t lo = (rb + 0x7fffu + ((rb >> 16) & 1u)) >> 16;
    return hi | lo;
}
__device__ __forceinline__ float unpackf(uint32_t u) {
    return __uint_as_float(u & 0xffff0000u) + __uint_as_float(u << 16);
}

__device__ __forceinline__ float wave_sum(float v) {
#pragma unroll
    for (int o = 32; o > 0; o >>= 1) v += __shfl_down(v, o, 64);
    return v;
}
__device__ __forceinline__ float wave_max(float v) {
#pragma unroll
    for (int o = 32; o > 0; o >>= 1) v = fmaxf(v, __shfl_down(v, o, 64));
    return v;
}

// ---------------------------------------------------------------------------
// K0: mask prep + exact EDT (one block per batch, all in LDS). 1024 threads
// (R7: 16 waves/CU hides the LDS-dependent fminf chains; was 117us @ 256thr).
// ---------------------------------------------------------------------------
__global__ __launch_bounds__(1024) void mask_edt_kernel(
    const int* __restrict__ mask, float* __restrict__ ms, float* __restrict__ mbg,
    float* __restrict__ dist, float* __restrict__ cnt)
{
    __shared__ float sm[4096];
    __shared__ float sg[4096];
    __shared__ float red[32];

    const int b = blockIdx.x;
    const int t = threadIdx.x;
    const int wid = t >> 6, lane = t & 63;
    const int* mb = mask + b * (HM * HM);

#pragma unroll
    for (int u = 0; u < 4; ++u) {
        int p = u * 1024 + t;
        int i = p >> 6, j = p & 63;
        sm[p] = (float)mb[(i * 4) * HM + (j * 4)];   // nearest: src = 4*dst
    }
    __syncthreads();

    float cfg = 0.f, cbg = 0.f;
#pragma unroll
    for (int u = 0; u < 4; ++u) {
        int p = u * 1024 + t;
        int i = p >> 6, j = p & 63;
        float mx = 0.f;
#pragma unroll
        for (int di = -1; di <= 1; ++di) {
            int ii = i + di;
            if (ii < 0 || ii > 63) continue;
#pragma unroll
            for (int dj = -1; dj <= 1; ++dj) {
                int jj = j + dj;
                if (jj < 0 || jj > 63) continue;
                mx = fmaxf(mx, sm[ii * 64 + jj]);
            }
        }
        float m = sm[p];
        float bg = fmaxf(mx - m, 0.f);
        cfg += m; cbg += bg;
        ms[b * NPIX + p] = m;
        mbg[b * NPIX + p] = bg;
    }
    float s1 = wave_sum(cfg), s2 = wave_sum(cbg);
    if (lane == 0) { red[wid] = s1; red[16 + wid] = s2; }
    __syncthreads();
    if (t == 0) {
        float a = 0.f, g = 0.f;
#pragma unroll
        for (int w = 0; w < 16; ++w) { a += red[w]; g += red[16 + w]; }
        cnt[b] = a; cnt[8 + b] = g;
    }

    // EDT pass 1: g[i][j] = min_{i'} |i-i'| + 128*(1 - m[i'][j])
#pragma unroll 1
    for (int u = 0; u < 4; ++u) {
        int p = u * 1024 + t;
        int i = p >> 6, j = p & 63;
        float fi = (float)i;
        float best = 1e30f;
#pragma unroll 8
        for (int ii = 0; ii < 64; ++ii) {
            float v = fabsf(fi - (float)ii) + 128.f * (1.f - sm[ii * 64 + j]);
            best = fminf(best, v);
        }
        sg[p] = best;
    }
    __syncthreads();

    // EDT pass 2: d = sqrt(min_{j'} g[i][j']^2 + (j-j')^2)
    float dmx = 0.f;
#pragma unroll 1
    for (int u = 0; u < 4; ++u) {
        int p = u * 1024 + t;
        int i = p >> 6, j = p & 63;
        float fj = (float)j;
        float best = 1e30f;
#pragma unroll 8
        for (int jj = 0; jj < 64; ++jj) {
            float g = sg[i * 64 + jj];           // wave-uniform -> broadcast
            float dj = fj - (float)jj;
            best = fminf(best, fmaf(g, g, dj * dj));
        }
        float d = sqrtf(best);
        sm[p] = d;                               // reuse sm for d (all sm reads done)
        dmx = fmaxf(dmx, d);
    }
    __syncthreads();
    float mW = wave_max(dmx);
    if (lane == 0) red[wid] = mW;
    __syncthreads();
    float dmax = red[0];
#pragma unroll
    for (int w = 1; w < 16; ++w) dmax = fmaxf(dmax, red[w]);
    dmax += 1e-6f;
#pragma unroll
    for (int u = 0; u < 4; ++u) {
        int p = u * 1024 + t;
        dist[b * NPIX + p] = sm[p] / dmax;
    }
}

// ---------------------------------------------------------------------------
// K1: p_contrast (fp32 exact)
// ---------------------------------------------------------------------------
__global__ __launch_bounds__(256) void pcontrast_kernel(
    const float* __restrict__ F, const float* __restrict__ ms,
    const float* __restrict__ mbg, const float* __restrict__ cnt,
    float* __restrict__ pc)
{
    const int c = blockIdx.x, b = blockIdx.y, t = threadIdx.x;
    const float4* f4 = (const float4*)(F + ((size_t)b * CC + c) * NPIX);
    const float4* m4 = (const float4*)(ms + (size_t)b * NPIX);
    const float4* g4 = (const float4*)(mbg + (size_t)b * NPIX);
    float sfg = 0.f, sbg = 0.f;
#pragma unroll 4
    for (int idx = t; idx < NPIX / 4; idx += 256) {
        float4 v = f4[idx], m = m4[idx], g = g4[idx];
        sfg += v.x * m.x + v.y * m.y + v.z * m.z + v.w * m.w;
        sbg += v.x * g.x + v.y * g.y + v.z * g.z + v.w * g.w;
    }
    __shared__ float r1[4], r2[4];
    sfg = wave_sum(sfg); sbg = wave_sum(sbg);
    int wid = t >> 6, lane = t & 63;
    if (lane == 0) { r1[wid] = sfg; r2[wid] = sbg; }
    __syncthreads();
    if (t == 0) {
        float a = r1[0] + r1[1] + r1[2] + r1[3];
        float g = r2[0] + r2[1] + r2[2] + r2[3];
        pc[b * CC + c] = a / (cnt[b] + 1e-8f) - g / (cnt[8 + b] + 1e-8f);
    }
}

// ---------------------------------------------------------------------------
// K2: transpose f_s [b][c][p] f32  ->  packed u32 [b][p][c]
// ---------------------------------------------------------------------------
__global__ __launch_bounds__(256) void transpose_pack(
    const float* __restrict__ F, uint32_t* __restrict__ Fp)
{
    __shared__ float sm[64][65];
    const int b  = blockIdx.z;
    const int c0 = blockIdx.y * 64;
    const int p0 = blockIdx.x * 64;
    const int t  = threadIdx.x;
    const float* Fb = F + ((size_t)b * CC + c0) * NPIX + p0;
#pragma unroll
    for (int s = 0; s < 4; ++s) {
        int cl = s * 16 + (t >> 4);
        float4 v = *(const float4*)&Fb[(size_t)cl * NPIX + (t & 15) * 4];
        *(float4*)&sm[cl][(t & 15) * 4] = v;
    }
    __syncthreads();
    const int lane = t & 63, w = t >> 6;
    uint32_t* Op = Fp + ((size_t)b * NPIX + p0) * CC + c0;
#pragma unroll
    for (int s = 0; s < 16; ++s) {
        int pl = s * 4 + w;
        Op[(size_t)pl * CC + lane] = packbf(sm[lane][pl]);   // pitch 65 -> 2-way, free
    }
}

// ---------------------------------------------------------------------------
// K3: pack weights (gate_w [512][512], fusion_w [512][513] -> first 512 cols)
// ---------------------------------------------------------------------------
__global__ __launch_bounds__(256) void pack_weights(
    const float* __restrict__ gw, const float* __restrict__ fw,
    uint32_t* __restrict__ gwp, uint32_t* __restrict__ fwp)
{
    const int o = blockIdx.x, t = threadIdx.x;
#pragma unroll 2
    for (int c = t; c < CC; c += 256) {
        gwp[o * CC + c] = packbf(gw[o * CC + c]);
        fwp[o * CC + c] = packbf(fw[o * (CC + 1) + c]);
    }
}

// ---------------------------------------------------------------------------
// K4/K5: bf16-split MFMA GEMM (3 terms: hi*hi + hi*lo + lo*hi), 128x128 tile,
// BK=32, 16x16x32 MFMA. Staging via global_load_lds w=16, both-sides XOR
// swizzle (rule #21; bank audit in R4 notes).
// R10 changes (counter-separable):
//  (1) __launch_bounds__(256,4): all 4 blocks/CU of work co-resident
//      (LDS 4x32KB=128<=160KB, VGPR 76<=128) -> OccupancyPercent 21->~40,
//      doubles MFMA||staging overlap (m114).
//  (2) bijective XCD-chunked blockIdx swizzle (T1/m204; nwg=1024, %8==0):
//      panel-sharing blocks (mode0: 4 consecutive x-blocks share an A m-panel;
//      mode1: y-blocks share a B n-panel, stride gridDim.x=32 < chunk 128)
//      become co-resident on ONE XCD's L2 -> FETCH_SIZE 200->~145MB,
//      staging latency ~900cy HBM -> ~200cy L2-hit.
// MODE 0 (gate):  A=f_s_pk[p][c] (batched), B=gate_wp[o][c];
//   epilogue f_pur = f_s + sigmoid(acc+bias)*pc -> packed u32 [p][c]
// MODE 1 (fusion): A=fus_wp[o][c], B=f_pur_pk[p][c] (batched);
//   epilogue out[o][p] = relu(acc + bias + w_last*dist[p]) (f32)
// ---------------------------------------------------------------------------
template <int MODE>
__global__ __launch_bounds__(256, 4) void mfma_gemm(
    const uint32_t* __restrict__ Apk, const uint32_t* __restrict__ Bpk,
    long aStride, long bStride,
    const float* __restrict__ bias,
    const float* __restrict__ aux,      // MODE0: pc[b][512]; MODE1: dist[b][4096]
    const float* __restrict__ wsrc,     // MODE1: fusion_w f32 (last col); MODE0 unused
    void* __restrict__ outp)
{
    // --- XCD-chunked swizzle: dispatch order lin -> chunked id swz ---------
    const int gx = gridDim.x, gy = gridDim.y;
    const int nwg = gx * gy * gridDim.z;                 // 1024, %8==0
    int lin = (blockIdx.z * gy + blockIdx.y) * gx + blockIdx.x;
    int cpx = nwg >> 3;
    int swz = (lin & 7) * cpx + (lin >> 3);
    const int bx = swz % gx;
    const int by = (swz / gx) % gy;
    const int b  = swz / (gx * gy);

    const int nBase = bx * 128;
    const int mBase = by * 128;
    const int tid   = threadIdx.x;
    const int lane  = tid & 63, wid = tid >> 6;
    const int wr    = wid >> 1, wc = wid & 1;

    __shared__ uint32_t As[128 * 32];
    __shared__ uint32_t Bs[128 * 32];

    const uint32_t* Ab = Apk + (size_t)b * aStride;
    const uint32_t* Bb = Bpk + (size_t)b * bStride;

    f32x4 acc[4][4];
#pragma unroll
    for (int i = 0; i < 4; ++i)
#pragma unroll
        for (int j = 0; j < 4; ++j) acc[i][j] = (f32x4){0.f, 0.f, 0.f, 0.f};

    const int l8 = lane >> 3;                 // row within 8-row group
    const int k16src = (lane & 7) ^ l8;       // swizzled 16B-unit on the SOURCE
    const int fr = lane & 15;
    const int kc = lane >> 4;                 // k-chunk 0..3 (8 k each)

    for (int it = 0; it < 16; ++it) {
        const int ktU = it * 32;
        // stage A,B tiles: 128 rows x 32 u32; 4 rounds x 4 waves x 1KB each
#pragma unroll
        for (int r = 0; r < 4; ++r) {
            int grp = r * 4 + wid;
            int row = grp * 8 + l8;
            const uint32_t* gA = Ab + (size_t)(mBase + row) * CC + ktU + k16src * 4;
            const uint32_t* gB = Bb + (size_t)(nBase + row) * CC + ktU + k16src * 4;
            __builtin_amdgcn_global_load_lds(
                (const __attribute__((address_space(1))) uint32_t*)gA,
                (__attribute__((address_space(3))) uint32_t*)&As[grp * 256 + lane * 4], 16, 0, 0);
            __builtin_amdgcn_global_load_lds(
                (const __attribute__((address_space(1))) uint32_t*)gB,
                (__attribute__((address_space(3))) uint32_t*)&Bs[grp * 256 + lane * 4], 16, 0, 0);
        }
        __syncthreads();

        // A fragments (4 m-frags), unpack hi/lo
        short8 hA[4], lA[4];
#pragma unroll
        for (int fm = 0; fm < 4; ++fm) {
            int row = wr * 64 + fm * 16 + fr;
            int base = row * 32, s = row & 7;
            uint4 x0 = *(const uint4*)&As[base + (((kc * 2)     ^ s) << 2)];
            uint4 x1 = *(const uint4*)&As[base + (((kc * 2 + 1) ^ s) << 2)];
            uint32_t pk[8] = {x0.x, x0.y, x0.z, x0.w, x1.x, x1.y, x1.z, x1.w};
#pragma unroll
            for (int j = 0; j < 8; ++j) {
                hA[fm][j] = (short)(pk[j] >> 16);
                lA[fm][j] = (short)(pk[j] & 0xffffu);
            }
        }
        // B fragments one n-frag at a time; 3-term MFMA
#pragma unroll
        for (int fn = 0; fn < 4; ++fn) {
            int row = wc * 64 + fn * 16 + fr;
            int base = row * 32, s = row & 7;
            uint4 x0 = *(const uint4*)&Bs[base + (((kc * 2)     ^ s) << 2)];
            uint4 x1 = *(const uint4*)&Bs[base + (((kc * 2 + 1) ^ s) << 2)];
            uint32_t pk[8] = {x0.x, x0.y, x0.z, x0.w, x1.x, x1.y, x1.z, x1.w};
            short8 hB, lB;
#pragma unroll
            for (int j = 0; j < 8; ++j) {
                hB[j] = (short)(pk[j] >> 16);
                lB[j] = (short)(pk[j] & 0xffffu);
            }
#pragma unroll
            for (int fm = 0; fm < 4; ++fm) {
                acc[fm][fn] = __builtin_amdgcn_mfma_f32_16x16x32_bf16(hA[fm], hB, acc[fm][fn], 0, 0, 0);
                acc[fm][fn] = __builtin_amdgcn_mfma_f32_16x16x32_bf16(hA[fm], lB, acc[fm][fn], 0, 0, 0);
                acc[fm][fn] = __builtin_amdgcn_mfma_f32_16x16x32_bf16(lA[fm], hB, acc[fm][fn], 0, 0, 0);
            }
        }
        __syncthreads();
    }

    // epilogue. C/D layout: col(n) = lane&15, row(m) = (lane>>4)*4 + reg
    const int rrow = (lane >> 4) * 4;
    if constexpr (MODE == 0) {
        uint32_t* fpur = (uint32_t*)outp;
#pragma unroll
        for (int fn = 0; fn < 4; ++fn) {
            int o = nBase + wc * 64 + fn * 16 + fr;
            float bo  = bias[o];
            float pco = aux[(size_t)b * CC + o];
#pragma unroll
            for (int fm = 0; fm < 4; ++fm) {
#pragma unroll
                for (int r = 0; r < 4; ++r) {
                    int p = mBase + wr * 64 + fm * 16 + rrow + r;
                    size_t idx = (size_t)p * CC + o;
                    float fs = unpackf(Ab[idx]);
                    float z = acc[fm][fn][r] + bo;
                    float g = 1.f / (1.f + expf(-z));
                    fpur[(size_t)b * NPIX * CC + idx] = packbf(fs + g * pco);
                }
            }
        }
    } else {
        float* Out = (float*)outp;
#pragma unroll
        for (int fn = 0; fn < 4; ++fn) {
            int p = nBase + wc * 64 + fn * 16 + fr;
            float dv = aux[(size_t)b * NPIX + p];
#pragma unroll
            for (int fm = 0; fm < 4; ++fm) {
#pragma unroll
                for (int r = 0; r < 4; ++r) {
                    int o = mBase + wr * 64 + fm * 16 + rrow + r;
                    float z = acc[fm][fn][r] + bias[o] + wsrc[(size_t)o * (CC + 1) + CC] * dv;
                    Out[((size_t)b * CC + o) * NPIX + p] = fmaxf(z, 0.f);
                }
            }
        }
    }
}

extern "C" void kernel_launch(void* const* d_in, const int* in_sizes, int n_in,
                              void* d_out, int out_size, void* d_ws, size_t ws_size,
                              hipStream_t stream)
{
    const float* f_s      = (const float*)d_in[0];
    const int*   mask     = (const int*)d_in[1];
    const float* gate_w   = (const float*)d_in[2];
    const float* gate_b   = (const float*)d_in[3];
    const float* fusion_w = (const float*)d_in[4];
    const float* fusion_b = (const float*)d_in[5];
    float* out = (float*)d_out;
    float*    wsf = (float*)d_ws;
    uint32_t* wsu = (uint32_t*)d_ws;

    float* ms   = wsf + WS_MS;
    float* mbg  = wsf + WS_MBG;
    float* dist = wsf + WS_DIST;
    float* cnt  = wsf + WS_CNT;
    float* pc   = wsf + WS_PC;
    uint32_t* gwp  = wsu + WS_GWP;
    uint32_t* fwp  = wsu + WS_FWP;
    uint32_t* fspk = wsu + WS_FSPK;
    uint32_t* fppk = wsu + WS_FPPK;

    hipLaunchKernelGGL(mask_edt_kernel, dim3(NB), dim3(1024), 0, stream,
                       mask, ms, mbg, dist, cnt);
    hipLaunchKernelGGL(pack_weights, dim3(CC), dim3(256), 0, stream,
                       gate_w, fusion_w, gwp, fwp);
    hipLaunchKernelGGL(transpose_pack, dim3(NPIX / 64, CC / 64, NB), dim3(256), 0, stream,
                       f_s, fspk);
    hipLaunchKernelGGL(pcontrast_kernel, dim3(CC, NB), dim3(256), 0, stream,
                       f_s, ms, mbg, cnt, pc);
    // GEMM-1: M=p (4096), N=o (512). A=f_s_pk (batched), B=gate_wp.
    hipLaunchKernelGGL((mfma_gemm<0>), dim3(CC / 128, NPIX / 128, NB), dim3(256), 0, stream,
                       fspk, gwp, (long)NPIX * CC, 0L, gate_b, pc, (const float*)nullptr,
                       (void*)fppk);
    // GEMM-2: M=o (512), N=p (4096). A=fus_wp, B=f_pur_pk (batched).
    hipLaunchKernelGGL((mfma_gemm<1>), dim3(NPIX / 128, CC / 128, NB), dim3(256), 0, stream,
                       fwp, fppk, 0L, (long)NPIX * CC, fusion_b, dist, fusion_w,
                       (void*)out);
}

// Round 12
// 344.497 us; speedup vs baseline: 1.1757x; 1.1757x over previous
//
#include <hip/hip_runtime.h>
#include <math.h>

// Problem constants
#define NB 8
#define CC 512
#define NPIX 4096   // 64*64
#define HM 256

// Workspace layout (4-byte units). Total ~130.4 MiB.
#define WS_MS    0                  // [8][4096] m_s (f32)
#define WS_MBG   32768              // [8][4096] m_bg (f32)
#define WS_DIST  65536              // [8][4096] EDT (f32)
#define WS_CNT   98304              // [16]
#define WS_PC    98320              // [8][512] p_contrast (f32)
#define WS_GWP   102416             // [512][512] gate_w packed u32
#define WS_FWP   364560             // [512][512] fusion_w packed u32
#define WS_FSPK  626704             // [8][4096][512] f_s packed u32 ([p][c] layout!)
#define WS_FPPK  17403920           // [8][4096][512] f_pur packed u32

typedef __attribute__((ext_vector_type(8))) short short8;
typedef __attribute__((ext_vector_type(4))) float f32x4;

// ---- bf16 split helpers: u32 = (bf16(x)<<16) | bf16(x - bf16(x)) -----------
__device__ __forceinline__ uint32_t packbf(float x) {
    uint32_t b = __float_as_uint(x);
    uint32_t hi = (b + 0x7fffu + ((b >> 16) & 1u)) & 0xffff0000u;   // RNE to bf16
    float rem = x - __uint_as_float(hi);
    uint32_t rb = __float_as_uint(rem);
    uint32_t lo = (rb + 0x7fffu + ((rb >> 16) & 1u)) >> 16;
    return hi | lo;
}
__device__ __forceinline__ float unpackf(uint32_t u) {
    return __uint_as_float(u & 0xffff0000u) + __uint_as_float(u << 16);
}

__device__ __forceinline__ float wave_sum(float v) {
#pragma unroll
    for (int o = 32; o > 0; o >>= 1) v += __shfl_down(v, o, 64);
    return v;
}
__device__ __forceinline__ float wave_max(float v) {
#pragma unroll
    for (int o = 32; o > 0; o >>= 1) v = fmaxf(v, __shfl_down(v, o, 64));
    return v;
}

// ---------------------------------------------------------------------------
// K0: mask prep + exact EDT (one block per batch, all in LDS). 1024 threads.
// ---------------------------------------------------------------------------
__global__ __launch_bounds__(1024) void mask_edt_kernel(
    const int* __restrict__ mask, float* __restrict__ ms, float* __restrict__ mbg,
    float* __restrict__ dist, float* __restrict__ cnt)
{
    __shared__ float sm[4096];
    __shared__ float sg[4096];
    __shared__ float red[32];

    const int b = blockIdx.x;
    const int t = threadIdx.x;
    const int wid = t >> 6, lane = t & 63;
    const int* mb = mask + b * (HM * HM);

#pragma unroll
    for (int u = 0; u < 4; ++u) {
        int p = u * 1024 + t;
        int i = p >> 6, j = p & 63;
        sm[p] = (float)mb[(i * 4) * HM + (j * 4)];   // nearest: src = 4*dst
    }
    __syncthreads();

    float cfg = 0.f, cbg = 0.f;
#pragma unroll
    for (int u = 0; u < 4; ++u) {
        int p = u * 1024 + t;
        int i = p >> 6, j = p & 63;
        float mx = 0.f;
#pragma unroll
        for (int di = -1; di <= 1; ++di) {
            int ii = i + di;
            if (ii < 0 || ii > 63) continue;
#pragma unroll
            for (int dj = -1; dj <= 1; ++dj) {
                int jj = j + dj;
                if (jj < 0 || jj > 63) continue;
                mx = fmaxf(mx, sm[ii * 64 + jj]);
            }
        }
        float m = sm[p];
        float bg = fmaxf(mx - m, 0.f);
        cfg += m; cbg += bg;
        ms[b * NPIX + p] = m;
        mbg[b * NPIX + p] = bg;
    }
    float s1 = wave_sum(cfg), s2 = wave_sum(cbg);
    if (lane == 0) { red[wid] = s1; red[16 + wid] = s2; }
    __syncthreads();
    if (t == 0) {
        float a = 0.f, g = 0.f;
#pragma unroll
        for (int w = 0; w < 16; ++w) { a += red[w]; g += red[16 + w]; }
        cnt[b] = a; cnt[8 + b] = g;
    }

    // EDT pass 1
#pragma unroll 1
    for (int u = 0; u < 4; ++u) {
        int p = u * 1024 + t;
        int i = p >> 6, j = p & 63;
        float fi = (float)i;
        float best = 1e30f;
#pragma unroll 8
        for (int ii = 0; ii < 64; ++ii) {
            float v = fabsf(fi - (float)ii) + 128.f * (1.f - sm[ii * 64 + j]);
            best = fminf(best, v);
        }
        sg[p] = best;
    }
    __syncthreads();

    // EDT pass 2
    float dmx = 0.f;
#pragma unroll 1
    for (int u = 0; u < 4; ++u) {
        int p = u * 1024 + t;
        int i = p >> 6, j = p & 63;
        float fj = (float)j;
        float best = 1e30f;
#pragma unroll 8
        for (int jj = 0; jj < 64; ++jj) {
            float g = sg[i * 64 + jj];
            float dj = fj - (float)jj;
            best = fminf(best, fmaf(g, g, dj * dj));
        }
        float d = sqrtf(best);
        sm[p] = d;
        dmx = fmaxf(dmx, d);
    }
    __syncthreads();
    float mW = wave_max(dmx);
    if (lane == 0) red[wid] = mW;
    __syncthreads();
    float dmax = red[0];
#pragma unroll
    for (int w = 1; w < 16; ++w) dmax = fmaxf(dmax, red[w]);
    dmax += 1e-6f;
#pragma unroll
    for (int u = 0; u < 4; ++u) {
        int p = u * 1024 + t;
        dist[b * NPIX + p] = sm[p] / dmax;
    }
}

// ---------------------------------------------------------------------------
// K1: p_contrast (fp32 exact)
// ---------------------------------------------------------------------------
__global__ __launch_bounds__(256) void pcontrast_kernel(
    const float* __restrict__ F, const float* __restrict__ ms,
    const float* __restrict__ mbg, const float* __restrict__ cnt,
    float* __restrict__ pc)
{
    const int c = blockIdx.x, b = blockIdx.y, t = threadIdx.x;
    const float4* f4 = (const float4*)(F + ((size_t)b * CC + c) * NPIX);
    const float4* m4 = (const float4*)(ms + (size_t)b * NPIX);
    const float4* g4 = (const float4*)(mbg + (size_t)b * NPIX);
    float sfg = 0.f, sbg = 0.f;
#pragma unroll 4
    for (int idx = t; idx < NPIX / 4; idx += 256) {
        float4 v = f4[idx], m = m4[idx], g = g4[idx];
        sfg += v.x * m.x + v.y * m.y + v.z * m.z + v.w * m.w;
        sbg += v.x * g.x + v.y * g.y + v.z * g.z + v.w * g.w;
    }
    __shared__ float r1[4], r2[4];
    sfg = wave_sum(sfg); sbg = wave_sum(sbg);
    int wid = t >> 6, lane = t & 63;
    if (lane == 0) { r1[wid] = sfg; r2[wid] = sbg; }
    __syncthreads();
    if (t == 0) {
        float a = r1[0] + r1[1] + r1[2] + r1[3];
        float g = r2[0] + r2[1] + r2[2] + r2[3];
        pc[b * CC + c] = a / (cnt[b] + 1e-8f) - g / (cnt[8 + b] + 1e-8f);
    }
}

// ---------------------------------------------------------------------------
// K2: transpose f_s [b][c][p] f32  ->  packed u32 [b][p][c]
// ---------------------------------------------------------------------------
__global__ __launch_bounds__(256) void transpose_pack(
    const float* __restrict__ F, uint32_t* __restrict__ Fp)
{
    __shared__ float sm[64][65];
    const int b  = blockIdx.z;
    const int c0 = blockIdx.y * 64;
    const int p0 = blockIdx.x * 64;
    const int t  = threadIdx.x;
    const float* Fb = F + ((size_t)b * CC + c0) * NPIX + p0;
#pragma unroll
    for (int s = 0; s < 4; ++s) {
        int cl = s * 16 + (t >> 4);
        float4 v = *(const float4*)&Fb[(size_t)cl * NPIX + (t & 15) * 4];
        *(float4*)&sm[cl][(t & 15) * 4] = v;
    }
    __syncthreads();
    const int lane = t & 63, w = t >> 6;
    uint32_t* Op = Fp + ((size_t)b * NPIX + p0) * CC + c0;
#pragma unroll
    for (int s = 0; s < 16; ++s) {
        int pl = s * 4 + w;
        Op[(size_t)pl * CC + lane] = packbf(sm[lane][pl]);
    }
}

// ---------------------------------------------------------------------------
// K3: pack weights
// ---------------------------------------------------------------------------
__global__ __launch_bounds__(256) void pack_weights(
    const float* __restrict__ gw, const float* __restrict__ fw,
    uint32_t* __restrict__ gwp, uint32_t* __restrict__ fwp)
{
    const int o = blockIdx.x, t = threadIdx.x;
#pragma unroll 2
    for (int c = t; c < CC; c += 256) {
        gwp[o * CC + c] = packbf(gw[o * CC + c]);
        fwp[o * CC + c] = packbf(fw[o * (CC + 1) + c]);
    }
}

// ---------------------------------------------------------------------------
// K4/K5: bf16-split MFMA GEMM, 128x128 tile, BK=32, 16x16x32 MFMA.
// R11 structural change (T3-minimum 2-phase double-buffer, issue-early):
//   prologue: STAGE(buf0, k=0); sync
//   loop x8:  STAGE(buf1, k+1); COMPUTE(buf0); sync    <- prefetch hides under
//             STAGE(buf0, k+2); COMPUTE(buf1); sync       compute; the vmcnt(0)
//                                                          in syncthreads now
//                                                          waits on ~1000cy-old
//                                                          loads, not fresh ones
// 4 distinct static __shared__ arrays + macro inlining keep all buffer refs
// compile-time so alias analysis can't pin conservative waits (R10 lesson:
// MfmaUtil stuck at 18-19% in the serialized stage->drain->compute shape).
// launch_bounds back to (256,2): R10's (256,4) squeezed VGPR 76->64 and
// halved VALUBusy. LDS 64KB/block -> 2 blocks/CU. XCD swizzle retained
// (FETCH 200->81MB confirmed in R10).
// ---------------------------------------------------------------------------
#define STAGE_TILE(dA, dB, ktU)                                                          \
    do {                                                                                 \
        _Pragma("unroll")                                                                \
        for (int r_ = 0; r_ < 4; ++r_) {                                                 \
            int grp_ = r_ * 4 + wid;                                                     \
            int row_ = grp_ * 8 + l8;                                                    \
            const uint32_t* gA_ = Ab + (size_t)(mBase + row_) * CC + (ktU) + k16src * 4; \
            const uint32_t* gB_ = Bb + (size_t)(nBase + row_) * CC + (ktU) + k16src * 4; \
            __builtin_amdgcn_global_load_lds(                                            \
                (const __attribute__((address_space(1))) uint32_t*)gA_,                  \
                (__attribute__((address_space(3))) uint32_t*)&dA[grp_ * 256 + lane * 4], \
                16, 0, 0);                                                               \
            __builtin_amdgcn_global_load_lds(                                            \
                (const __attribute__((address_space(1))) uint32_t*)gB_,                  \
                (__attribute__((address_space(3))) uint32_t*)&dB[grp_ * 256 + lane * 4], \
                16, 0, 0);                                                               \
        }                                                                                \
    } while (0)

#define COMPUTE_TILE(sA, sB)                                                             \
    do {                                                                                 \
        short8 hA_[4], lA_[4];                                                           \
        _Pragma("unroll")                                                                \
        for (int fm_ = 0; fm_ < 4; ++fm_) {                                              \
            int row_ = wr * 64 + fm_ * 16 + fr;                                          \
            int base_ = row_ * 32, s_ = row_ & 7;                                        \
            uint4 x0_ = *(const uint4*)&sA[base_ + (((kc * 2)     ^ s_) << 2)];          \
            uint4 x1_ = *(const uint4*)&sA[base_ + (((kc * 2 + 1) ^ s_) << 2)];          \
            uint32_t pk_[8] = {x0_.x, x0_.y, x0_.z, x0_.w, x1_.x, x1_.y, x1_.z, x1_.w};  \
            _Pragma("unroll")                                                            \
            for (int j_ = 0; j_ < 8; ++j_) {                                             \
                hA_[fm_][j_] = (short)(pk_[j_] >> 16);                                   \
                lA_[fm_][j_] = (short)(pk_[j_] & 0xffffu);                               \
            }                                                                            \
        }                                                                                \
        _Pragma("unroll")                                                                \
        for (int fn_ = 0; fn_ < 4; ++fn_) {                                              \
            int row_ = wc * 64 + fn_ * 16 + fr;                                          \
            int base_ = row_ * 32, s_ = row_ & 7;                                        \
            uint4 x0_ = *(const uint4*)&sB[base_ + (((kc * 2)     ^ s_) << 2)];          \
            uint4 x1_ = *(const uint4*)&sB[base_ + (((kc * 2 + 1) ^ s_) << 2)];          \
            uint32_t pk_[8] = {x0_.x, x0_.y, x0_.z, x0_.w, x1_.x, x1_.y, x1_.z, x1_.w};  \
            short8 hB_, lB_;                                                             \
            _Pragma("unroll")                                                            \
            for (int j_ = 0; j_ < 8; ++j_) {                                             \
                hB_[j_] = (short)(pk_[j_] >> 16);                                        \
                lB_[j_] = (short)(pk_[j_] & 0xffffu);                                    \
            }                                                                            \
            _Pragma("unroll")                                                            \
            for (int fm_ = 0; fm_ < 4; ++fm_) {                                          \
                acc[fm_][fn_] = __builtin_amdgcn_mfma_f32_16x16x32_bf16(hA_[fm_], hB_, acc[fm_][fn_], 0, 0, 0); \
                acc[fm_][fn_] = __builtin_amdgcn_mfma_f32_16x16x32_bf16(hA_[fm_], lB_, acc[fm_][fn_], 0, 0, 0); \
                acc[fm_][fn_] = __builtin_amdgcn_mfma_f32_16x16x32_bf16(lA_[fm_], hB_, acc[fm_][fn_], 0, 0, 0); \
            }                                                                            \
        }                                                                                \
    } while (0)

template <int MODE>
__global__ __launch_bounds__(256, 2) void mfma_gemm(
    const uint32_t* __restrict__ Apk, const uint32_t* __restrict__ Bpk,
    long aStride, long bStride,
    const float* __restrict__ bias,
    const float* __restrict__ aux,      // MODE0: pc[b][512]; MODE1: dist[b][4096]
    const float* __restrict__ wsrc,     // MODE1: fusion_w f32 (last col); MODE0 unused
    void* __restrict__ outp)
{
    // XCD-chunked bijective swizzle (nwg=1024, %8==0)
    const int gx = gridDim.x, gy = gridDim.y;
    const int nwg = gx * gy * gridDim.z;
    int lin = (blockIdx.z * gy + blockIdx.y) * gx + blockIdx.x;
    int cpx = nwg >> 3;
    int swz = (lin & 7) * cpx + (lin >> 3);
    const int bx = swz % gx;
    const int by = (swz / gx) % gy;
    const int b  = swz / (gx * gy);

    const int nBase = bx * 128;
    const int mBase = by * 128;
    const int tid   = threadIdx.x;
    const int lane  = tid & 63, wid = tid >> 6;
    const int wr    = wid >> 1, wc = wid & 1;

    __shared__ uint32_t As0[128 * 32];
    __shared__ uint32_t Bs0[128 * 32];
    __shared__ uint32_t As1[128 * 32];
    __shared__ uint32_t Bs1[128 * 32];

    const uint32_t* Ab = Apk + (size_t)b * aStride;
    const uint32_t* Bb = Bpk + (size_t)b * bStride;

    f32x4 acc[4][4];
#pragma unroll
    for (int i = 0; i < 4; ++i)
#pragma unroll
        for (int j = 0; j < 4; ++j) acc[i][j] = (f32x4){0.f, 0.f, 0.f, 0.f};

    const int l8 = lane >> 3;                 // row within 8-row group
    const int k16src = (lane & 7) ^ l8;       // swizzled 16B-unit on the SOURCE
    const int fr = lane & 15;
    const int kc = lane >> 4;                 // k-chunk 0..3 (8 k each)

    // prologue: tile 0 into buf0
    STAGE_TILE(As0, Bs0, 0);
    __syncthreads();

#pragma unroll 1
    for (int it2 = 0; it2 < 8; ++it2) {
        const int ktU1 = it2 * 64 + 32;       // odd tile (2*it2+1) in u32 units
        STAGE_TILE(As1, Bs1, ktU1);           // issue-early: hides under compute
        COMPUTE_TILE(As0, Bs0);
        __syncthreads();                      // prefetch landed + buf0 reads done
        if (it2 < 7) {
            STAGE_TILE(As0, Bs0, ktU1 + 32);  // even tile (2*it2+2)
        }
        COMPUTE_TILE(As1, Bs1);
        __syncthreads();
    }

    // epilogue. C/D layout: col(n) = lane&15, row(m) = (lane>>4)*4 + reg
    const int rrow = (lane >> 4) * 4;
    if constexpr (MODE == 0) {
        uint32_t* fpur = (uint32_t*)outp;
#pragma unroll
        for (int fn = 0; fn < 4; ++fn) {
            int o = nBase + wc * 64 + fn * 16 + fr;
            float bo  = bias[o];
            float pco = aux[(size_t)b * CC + o];
#pragma unroll
            for (int fm = 0; fm < 4; ++fm) {
#pragma unroll
                for (int r = 0; r < 4; ++r) {
                    int p = mBase + wr * 64 + fm * 16 + rrow + r;
                    size_t idx = (size_t)p * CC + o;
                    float fs = unpackf(Ab[idx]);
                    float z = acc[fm][fn][r] + bo;
                    float g = 1.f / (1.f + expf(-z));
                    fpur[(size_t)b * NPIX * CC + idx] = packbf(fs + g * pco);
                }
            }
        }
    } else {
        float* Out = (float*)outp;
#pragma unroll
        for (int fn = 0; fn < 4; ++fn) {
            int p = nBase + wc * 64 + fn * 16 + fr;
            float dv = aux[(size_t)b * NPIX + p];
#pragma unroll
            for (int fm = 0; fm < 4; ++fm) {
#pragma unroll
                for (int r = 0; r < 4; ++r) {
                    int o = mBase + wr * 64 + fm * 16 + rrow + r;
                    float z = acc[fm][fn][r] + bias[o] + wsrc[(size_t)o * (CC + 1) + CC] * dv;
                    Out[((size_t)b * CC + o) * NPIX + p] = fmaxf(z, 0.f);
                }
            }
        }
    }
}

extern "C" void kernel_launch(void* const* d_in, const int* in_sizes, int n_in,
                              void* d_out, int out_size, void* d_ws, size_t ws_size,
                              hipStream_t stream)
{
    const float* f_s      = (const float*)d_in[0];
    const int*   mask     = (const int*)d_in[1];
    const float* gate_w   = (const float*)d_in[2];
    const float* gate_b   = (const float*)d_in[3];
    const float* fusion_w = (const float*)d_in[4];
    const float* fusion_b = (const float*)d_in[5];
    float* out = (float*)d_out;
    float*    wsf = (float*)d_ws;
    uint32_t* wsu = (uint32_t*)d_ws;

    float* ms   = wsf + WS_MS;
    float* mbg  = wsf + WS_MBG;
    float* dist = wsf + WS_DIST;
    float* cnt  = wsf + WS_CNT;
    float* pc   = wsf + WS_PC;
    uint32_t* gwp  = wsu + WS_GWP;
    uint32_t* fwp  = wsu + WS_FWP;
    uint32_t* fspk = wsu + WS_FSPK;
    uint32_t* fppk = wsu + WS_FPPK;

    hipLaunchKernelGGL(mask_edt_kernel, dim3(NB), dim3(1024), 0, stream,
                       mask, ms, mbg, dist, cnt);
    hipLaunchKernelGGL(pack_weights, dim3(CC), dim3(256), 0, stream,
                       gate_w, fusion_w, gwp, fwp);
    hipLaunchKernelGGL(transpose_pack, dim3(NPIX / 64, CC / 64, NB), dim3(256), 0, stream,
                       f_s, fspk);
    hipLaunchKernelGGL(pcontrast_kernel, dim3(CC, NB), dim3(256), 0, stream,
                       f_s, ms, mbg, cnt, pc);
    // GEMM-1: M=p (4096), N=o (512). A=f_s_pk (batched), B=gate_wp.
    hipLaunchKernelGGL((mfma_gemm<0>), dim3(CC / 128, NPIX / 128, NB), dim3(256), 0, stream,
                       fspk, gwp, (long)NPIX * CC, 0L, gate_b, pc, (const float*)nullptr,
                       (void*)fppk);
    // GEMM-2: M=o (512), N=p (4096). A=fus_wp, B=f_pur_pk (batched).
    hipLaunchKernelGGL((mfma_gemm<1>), dim3(NPIX / 128, CC / 128, NB), dim3(256), 0, stream,
                       fwp, fppk, 0L, (long)NPIX * CC, fusion_b, dist, fusion_w,
                       (void*)out);
}